// Round 12
// baseline (170.971 us; speedup 1.0000x reference)
//
#include <hip/hip_runtime.h>
#include <math.h>

#define TEMP 0.01f

typedef __attribute__((ext_vector_type(8))) short short8;
typedef __attribute__((ext_vector_type(4))) float f32x4;
typedef __attribute__((ext_vector_type(4))) unsigned short ushort4_t;

// ---------------------------------------------------------------------------
// ws layout (floats from base):
//   accum   f32[3] @ 0   (correct, total_pos, total_loss)
//   counter int @ 3, counter2 int @ 4        (memset zeroes bytes [0,32))
//   posbuf  f32[4096*128] @ 16               (ends at float 524304)
//   P4      float4[4096*64] @ float 524304   ({nsum, 0, cw*sum_logit, nmax};
//             every slot written by exactly one thread -> no init, NO ATOMICS)
// 2 dispatches total: 32B memset + mega_kernel (tiles + ticketed finalize).
// ---------------------------------------------------------------------------

__device__ __forceinline__ unsigned bf16_hi_bits(float x) {
  unsigned u = __float_as_uint(x);
  return (u + 0x7FFFu + ((u >> 16) & 1u)) >> 16;  // RNE to bf16
}

struct HL { unsigned short h, l; };

__device__ __forceinline__ HL split1(float x) {
  unsigned hb = bf16_hi_bits(x);
  float hf = __uint_as_float(hb << 16);
  unsigned lb = bf16_hi_bits(x - hf);
  HL r;
  r.h = (unsigned short)hb;
  r.l = (unsigned short)lb;
  return r;
}

__device__ __forceinline__ void decode_ov(const int* __restrict__ ov_raw,
                                          int* s_class2, int* s_v2b,
                                          int* s_ov) {
  const int t = threadIdx.x;
  if (t < 64) {
    int v = (t < 32) ? ov_raw[t] : 0;
    bool valid = (t >= 32) || (v == 0) || (v == 1);
    unsigned long long okmask = __ballot(valid);
    bool as_int = (okmask == ~0ull);
    s_v2b[t] = 0;
    if (t < 32) {
      int o = as_int ? v : (((const unsigned char*)ov_raw)[t] ? 1 : 0);
      s_ov[t] = o;
      unsigned long long nz = __ballot((t < 32) && !o);
      int cum = __popcll(nz & ((1ull << t) - 1ull));
      int c2 = o ? t : 32 + cum;
      s_class2[t] = c2;
      s_v2b[c2] = t;
    }
  }
}

__device__ __forceinline__ int labf(int g, const int* s_class2) {
  return (g < 2048) ? (g >> 6) : s_class2[(g - 2048) >> 6];
}

__device__ __forceinline__ int slotf(int g, int cls, const int* s_v2b) {
  if (g < 2048) return g - (cls << 6);
  return ((cls < 32) ? 64 : 0) + (g - 2048 - (s_v2b[cls] << 6));
}

// ---------------------------------------------------------------------------
// One 128x128 tile — R6 in-kernel-split staging (bit-exact proven) +
// R11 LDS-transpose epilogue (no shuffles, no atomics).
// ---------------------------------------------------------------------------
__device__ __forceinline__ void compute_tile(
    int bi, int bj, bool diag,
    const float* __restrict__ f1, const float* __restrict__ f2,
    unsigned short (*Ah)[64], unsigned short (*Al)[64],
    unsigned short (*Bh)[64], unsigned short (*Bl)[64],
    const int* s_class2, const int* s_v2b,
    float4* __restrict__ P4, float* __restrict__ posbuf) {
  const int ibase = bi * 128, jbase = bj * 128;
  const float* asrc = (ibase < 2048) ? (f1 + (size_t)ibase * 128)
                                     : (f2 + (size_t)(ibase - 2048) * 128);
  const float* bsrc = (jbase < 2048) ? (f1 + (size_t)jbase * 128)
                                     : (f2 + (size_t)(jbase - 2048) * 128);
  const int t = threadIdx.x;
  const int l = t & 63;
  const int wid = t >> 6;
  const int wy = wid >> 1, wx = wid & 1;
  const int rr = l & 15;
  const int q = l >> 4;
  const int sw = l & 7;

  f32x4 acc[4][4];
#pragma unroll
  for (int mi = 0; mi < 4; ++mi)
#pragma unroll
    for (int ni = 0; ni < 4; ++ni) acc[mi][ni] = (f32x4)0.0f;

  const int kq = t & 15;
  const int r0 = t >> 4;
  const int stc = ((kq >> 1) ^ (r0 & 7)) * 8 + (kq & 1) * 4;

  for (int kc = 0; kc < 2; ++kc) {
    __syncthreads();  // protects LDS vs prior readers (incl. prior tile)
#pragma unroll
    for (int p = 0; p < 8; ++p) {
      const int r = r0 + 16 * p;
      const float4 va = *(const float4*)(asrc + (size_t)r * 128 + kc * 64 + kq * 4);
      ushort4_t ha, la;
      HL s;
      s = split1(va.x); ha.x = s.h; la.x = s.l;
      s = split1(va.y); ha.y = s.h; la.y = s.l;
      s = split1(va.z); ha.z = s.h; la.z = s.l;
      s = split1(va.w); ha.w = s.h; la.w = s.l;
      *(ushort4_t*)&Ah[r][stc] = ha;
      *(ushort4_t*)&Al[r][stc] = la;
      if (!diag) {
        const float4 vb = *(const float4*)(bsrc + (size_t)r * 128 + kc * 64 + kq * 4);
        ushort4_t hb, lb;
        s = split1(vb.x); hb.x = s.h; lb.x = s.l;
        s = split1(vb.y); hb.y = s.h; lb.y = s.l;
        s = split1(vb.z); hb.z = s.h; lb.z = s.l;
        s = split1(vb.w); hb.w = s.h; lb.w = s.l;
        *(ushort4_t*)&Bh[r][stc] = hb;
        *(ushort4_t*)&Bl[r][stc] = lb;
      }
    }
    __syncthreads();

#pragma unroll
    for (int s = 0; s < 2; ++s) {
      const int pb = ((((s << 2) | q)) ^ sw) << 3;
      short8 afh[4], afl[4], bfh[4], bfl[4];
#pragma unroll
      for (int mi = 0; mi < 4; ++mi) {
        const int ar = wy * 64 + mi * 16 + rr;
        afh[mi] = *(const short8*)&Ah[ar][pb];
        afl[mi] = *(const short8*)&Al[ar][pb];
        const int br = wx * 64 + mi * 16 + rr;
        bfh[mi] = diag ? *(const short8*)&Ah[br][pb]
                       : *(const short8*)&Bh[br][pb];
        bfl[mi] = diag ? *(const short8*)&Al[br][pb]
                       : *(const short8*)&Bl[br][pb];
      }
#pragma unroll
      for (int mi = 0; mi < 4; ++mi)
#pragma unroll
        for (int ni = 0; ni < 4; ++ni) {
          acc[mi][ni] = __builtin_amdgcn_mfma_f32_16x16x32_bf16(
              afh[mi], bfh[ni], acc[mi][ni], 0, 0, 0);
          acc[mi][ni] = __builtin_amdgcn_mfma_f32_16x16x32_bf16(
              afh[mi], bfl[ni], acc[mi][ni], 0, 0, 0);
          acc[mi][ni] = __builtin_amdgcn_mfma_f32_16x16x32_bf16(
              afl[mi], bfh[ni], acc[mi][ni], 0, 0, 0);
        }
    }
  }

  // -------- epilogue: LDS-transpose reductions (no shuffles, no atomics) ---
  const bool off = !diag;
  const float cw = ((ibase < 2048) != (jbase < 2048)) ? 0.5f : 1.0f;

  float* RowPn = (float*)&Ah[0][0];   // overlays: tile LDS dead after MFMA
  float* RowPl = (float*)&Al[0][0];
  float* RowPm = (float*)&Bh[0][0];
  float* ColPn = (float*)&Bl[0][0];
  float* ColPl = ColPn + 1024;
  float* ColPm = ColPn + 2048;

  int gj[4], lj[4];
#pragma unroll
  for (int ni = 0; ni < 4; ++ni) {
    gj[ni] = jbase + wx * 64 + ni * 16 + rr;
    lj[ni] = labf(gj[ni], s_class2);
  }

  float cnsum[4], cnmax[4], clsum[4];
#pragma unroll
  for (int ni = 0; ni < 4; ++ni) {
    cnsum[ni] = 0.f; cnmax[ni] = 0.f; clsum[ni] = 0.f;
  }

  __syncthreads();  // all waves done reading tile LDS before overlay writes

#pragma unroll
  for (int mi = 0; mi < 4; ++mi) {
#pragma unroll
    for (int reg = 0; reg < 4; ++reg) {
      const int gi = ibase + wy * 64 + mi * 16 + q * 4 + reg;
      const int li = labf(gi, s_class2);
      float rn = 0.f, rl = 0.f, rm = 0.f;
#pragma unroll
      for (int ni = 0; ni < 4; ++ni) {
        const int gjj = gj[ni];
        if (gi == gjj) continue;
        const float logit = acc[mi][ni][reg] * TEMP;
        const float e = __expf(logit);
        if (li == lj[ni]) {
          rl += logit;
          posbuf[(size_t)gi * 128 + slotf(gjj, li, s_v2b)] = e;
          if (off) {
            clsum[ni] += logit;
            posbuf[(size_t)gjj * 128 + slotf(gi, li, s_v2b)] = e;
          }
        } else {
          rn += e;
          rm = fmaxf(rm, e);
          if (off) {
            cnsum[ni] += e;
            cnmax[ni] = fmaxf(cnmax[ni], e);
          }
        }
      }
      const int widx = ((mi * 4 + reg) * 4 + wid) * 64 + l;
      RowPn[widx] = rn;
      RowPl[widx] = rl;
      RowPm[widx] = rm;
    }
  }
  if (off) {
#pragma unroll
    for (int ni = 0; ni < 4; ++ni) {
      const int widx = (ni * 4 + wid) * 64 + l;
      ColPn[widx] = cnsum[ni];
      ColPl[widx] = clsum[ni];
      ColPm[widx] = cnmax[ni];
    }
  }
  __syncthreads();

  // phase 2a: row reduce — thread t owns (row r = t>>1, col-half h = t&1)
  {
    const int r = t >> 1, h = t & 1;
    const int g = (((r >> 4) & 3) * 4) + (r & 3);      // mi*4+reg
    const int w2 = (r >> 6) * 2 + h;                   // wy*2+wx
    const int base = (g * 4 + w2) * 64 + ((r >> 2) & 3) * 16;
    const float4* pn = (const float4*)&RowPn[base];
    const float4* pl = (const float4*)&RowPl[base];
    const float4* pm = (const float4*)&RowPm[base];
    float ns = 0.f, ls = 0.f, nm = 0.f;
#pragma unroll
    for (int i = 0; i < 4; ++i) {
      const float4 a = pn[i], b = pl[i], c = pm[i];
      ns += a.x + a.y + a.z + a.w;
      ls += b.x + b.y + b.z + b.w;
      nm = fmaxf(nm, fmaxf(fmaxf(c.x, c.y), fmaxf(c.z, c.w)));
    }
    float4 v; v.x = ns; v.y = 0.f; v.z = cw * ls; v.w = nm;
    P4[(size_t)(ibase + r) * 64 + (bj * 2 + h)] = v;
  }

  // phase 2b: col reduce (off-diag only)
  if (off) {
    const int c = t >> 1, hy = t & 1;
    const int w2 = hy * 2 + (c >> 6);
    const int base = (((c >> 4) & 3) * 4 + w2) * 64 + (c & 15);
    float ns = 0.f, ls = 0.f, nm = 0.f;
#pragma unroll
    for (int q4 = 0; q4 < 4; ++q4) {
      const int idx = base + q4 * 16;
      ns += ColPn[idx];
      ls += ColPl[idx];
      nm = fmaxf(nm, ColPm[idx]);
    }
    float4 v; v.x = ns; v.y = 0.f; v.z = cw * ls; v.w = nm;
    P4[(size_t)(jbase + c) * 64 + (bi * 2 + hy)] = v;
  }
}

// ---------------------------------------------------------------------------
// Mega-kernel: 512 blocks (2/CU). 496 off-diag tiles + 16 blocks x 2 diag.
// After its tile(s) every block takes a completion ticket; the LAST 128
// tickets wait for all 512 commits, then finalize 32 rows each.
// Deadlock-safe: <=128 spinners occupy <=128 resident slots; all workers can
// always make progress and every block increments before (or without) spinning.
// ---------------------------------------------------------------------------
__global__ __launch_bounds__(256, 2) void mega_kernel(
    const float* __restrict__ f1, const float* __restrict__ f2,
    const int* __restrict__ ov_raw, float4* __restrict__ P4,
    float* __restrict__ posbuf, float* __restrict__ accum,
    int* __restrict__ counter, int* __restrict__ counter2,
    float* __restrict__ out) {
  __shared__ unsigned short Ah[128][64], Al[128][64];
  __shared__ unsigned short Bh[128][64], Bl[128][64];
  __shared__ int s_class2[32], s_v2b[64], s_ov[32];
  __shared__ int s_ticket;
  __shared__ float sc[4], sp[4], sl[4];

  decode_ov(ov_raw, s_class2, s_v2b, s_ov);

  const int bid = blockIdx.x;
  if (bid < 496) {
    int idx = bid, bi = 0;
    while (idx >= 31 - bi) { idx -= 31 - bi; ++bi; }
    const int bj = bi + 1 + idx;
    compute_tile(bi, bj, false, f1, f2, Ah, Al, Bh, Bl, s_class2, s_v2b, P4,
                 posbuf);
  } else {
    const int d = (bid - 496) * 2;
    compute_tile(d, d, true, f1, f2, Ah, Al, Bh, Bl, s_class2, s_v2b, P4,
                 posbuf);
    compute_tile(d + 1, d + 1, true, f1, f2, Ah, Al, Bh, Bl, s_class2, s_v2b,
                 P4, posbuf);
  }

  // ---- completion ticket ----
  __threadfence();  // release all P4/posbuf stores (device scope)
  const int t = threadIdx.x;
  if (t == 0) s_ticket = atomicAdd(counter, 1);
  __syncthreads();
  const int ticket = s_ticket;
  if (ticket < 384) return;  // worker done

  // ---- finalizer: wait for all 512 commits ----
  if (t == 0) {
    while (atomicAdd(counter, 0) < 512) __builtin_amdgcn_s_sleep(2);
  }
  __syncthreads();
  __threadfence();  // acquire

  const int slice = ticket - 384;  // 0..127 -> rows [slice*32, slice*32+32)
  const int w = t >> 6, lane = t & 63;
  float cnt_acc = 0.f, pos_acc = 0.f, loss_acc = 0.f;
  const int rbase = slice * 32 + w * 8;
  for (int i = 0; i < 8; ++i) {
    const int row = rbase + i;
    float4 p = P4[(size_t)row * 64 + lane];
#pragma unroll
    for (int m = 1; m < 64; m <<= 1) {
      p.x += __shfl_xor(p.x, m, 64);
      p.z += __shfl_xor(p.z, m, 64);
      p.w = fmaxf(p.w, __shfl_xor(p.w, m, 64));
    }
    const float nmax = p.w;
    const float2 pv = *(const float2*)&posbuf[(size_t)row * 128 + lane * 2];
    const int c = labf(row, s_class2);
    const bool both = (row < 2048) ? (s_ov[c] != 0) : (c < 32);
    const int size = both ? 128 : 64;
    int selfslot;
    if (row < 2048) selfslot = row - (c << 6);
    else selfslot = ((c < 32) ? 64 : 0) + (row - 2048 - (s_v2b[c] << 6));
    const int s0 = lane * 2;
    int h = 0;
    if (s0 < size && s0 != selfslot && pv.x > nmax) h++;
    if (s0 + 1 < size && s0 + 1 != selfslot && pv.y > nmax) h++;
    cnt_acc += (float)h;
    if (lane == 0) {
      const float pcw = both ? 95.f : 63.f;
      loss_acc += logf(p.x) * pcw - p.z;
      pos_acc += (float)(size - 1);
    }
  }
#pragma unroll
  for (int m = 1; m < 64; m <<= 1) {
    cnt_acc += __shfl_xor(cnt_acc, m, 64);
    pos_acc += __shfl_xor(pos_acc, m, 64);
    loss_acc += __shfl_xor(loss_acc, m, 64);
  }
  if (lane == 0) { sc[w] = cnt_acc; sp[w] = pos_acc; sl[w] = loss_acc; }
  __syncthreads();
  if (t == 0) {
    atomicAdd(&accum[0], sc[0] + sc[1] + sc[2] + sc[3]);
    atomicAdd(&accum[1], sp[0] + sp[1] + sp[2] + sp[3]);
    atomicAdd(&accum[2], sl[0] + sl[1] + sl[2] + sl[3]);
    __threadfence();
    const int tk2 = atomicAdd(counter2, 1);
    if (tk2 == 127) {
      const float c = atomicAdd(&accum[0], 0.0f);
      const float tp = atomicAdd(&accum[1], 0.0f);
      const float lo = atomicAdd(&accum[2], 0.0f);
      out[0] = c / tp;
      out[1] = lo / tp;
    }
  }
}

extern "C" void kernel_launch(void* const* d_in, const int* in_sizes, int n_in,
                              void* d_out, int out_size, void* d_ws,
                              size_t ws_size, hipStream_t stream) {
  const float* f1 = (const float*)d_in[0];
  const float* f2 = (const float*)d_in[1];
  const int* ov = (const int*)d_in[2];
  float* out = (float*)d_out;

  float* wsf = (float*)d_ws;
  int* wsi = (int*)d_ws;
  float* accum  = wsf;                 // 3 floats
  int* counter  = wsi + 3;             // 1 int
  int* counter2 = wsi + 4;             // 1 int
  float* posbuf = wsf + 16;            // 4096*128 -> ends at float 524304
  float4* P4    = (float4*)(wsf + 524304);  // 4096*64 float4 = 4 MB

  (void)hipMemsetAsync(accum, 0, 32, stream);

  mega_kernel<<<512, 256, 0, stream>>>(f1, f2, ov, P4, posbuf, accum, counter,
                                       counter2, out);
}

// Round 13
// 106.677 us; speedup vs baseline: 1.6027x; 1.6027x over previous
//
#include <hip/hip_runtime.h>
#include <math.h>

#define TEMP 0.01f

typedef __attribute__((ext_vector_type(8))) short short8;
typedef __attribute__((ext_vector_type(4))) float f32x4;
typedef __attribute__((ext_vector_type(4))) unsigned short ushort4_t;

// ---------------------------------------------------------------------------
// ws layout (floats from base):
//   accum   f32[3] @ 0, counter int @ 3       (memset zeroes bytes [0,32))
//   posbuf  f32[4096*128] @ 16                (ends at float 524304)
//   P4      float4[4096*64] @ float 524304    ({nsum, 0, cw*sum_logit, nmax};
//             every slot written by exactly one thread -> no init, NO ATOMICS)
// 3 dispatches: 32B memset + main (tiles) + finalize. Cross-block dataflow
// crosses kernel boundaries only (R12 lesson: device fences inside a hot
// kernel flush per-XCD L2 and cost ~3x).
// ---------------------------------------------------------------------------

__device__ __forceinline__ unsigned bf16_hi_bits(float x) {
  unsigned u = __float_as_uint(x);
  return (u + 0x7FFFu + ((u >> 16) & 1u)) >> 16;  // RNE to bf16
}

struct HL { unsigned short h, l; };

__device__ __forceinline__ HL split1(float x) {
  unsigned hb = bf16_hi_bits(x);
  float hf = __uint_as_float(hb << 16);
  unsigned lb = bf16_hi_bits(x - hf);
  HL r;
  r.h = (unsigned short)hb;
  r.l = (unsigned short)lb;
  return r;
}

__device__ __forceinline__ void decode_ov(const int* __restrict__ ov_raw,
                                          int* s_class2, int* s_v2b,
                                          int* s_ov) {
  const int t = threadIdx.x;
  if (t < 64) {
    int v = (t < 32) ? ov_raw[t] : 0;
    bool valid = (t >= 32) || (v == 0) || (v == 1);
    unsigned long long okmask = __ballot(valid);
    bool as_int = (okmask == ~0ull);
    s_v2b[t] = 0;
    if (t < 32) {
      int o = as_int ? v : (((const unsigned char*)ov_raw)[t] ? 1 : 0);
      s_ov[t] = o;
      unsigned long long nz = __ballot((t < 32) && !o);
      int cum = __popcll(nz & ((1ull << t) - 1ull));
      int c2 = o ? t : 32 + cum;
      s_class2[t] = c2;
      s_v2b[c2] = t;
    }
  }
}

__device__ __forceinline__ int labf(int g, const int* s_class2) {
  return (g < 2048) ? (g >> 6) : s_class2[(g - 2048) >> 6];
}

__device__ __forceinline__ int slotf(int g, int cls, const int* s_v2b) {
  if (g < 2048) return g - (cls << 6);
  return ((cls < 32) ? 64 : 0) + (g - 2048 - (s_v2b[cls] << 6));
}

// ---------------------------------------------------------------------------
// One 128x128 tile — R6 in-kernel-split staging (bit-exact proven) +
// R11 LDS-transpose epilogue (no shuffles, no atomics).
// ---------------------------------------------------------------------------
__device__ __forceinline__ void compute_tile(
    int bi, int bj, bool diag,
    const float* __restrict__ f1, const float* __restrict__ f2,
    unsigned short (*Ah)[64], unsigned short (*Al)[64],
    unsigned short (*Bh)[64], unsigned short (*Bl)[64],
    const int* s_class2, const int* s_v2b,
    float4* __restrict__ P4, float* __restrict__ posbuf) {
  const int ibase = bi * 128, jbase = bj * 128;
  const float* asrc = (ibase < 2048) ? (f1 + (size_t)ibase * 128)
                                     : (f2 + (size_t)(ibase - 2048) * 128);
  const float* bsrc = (jbase < 2048) ? (f1 + (size_t)jbase * 128)
                                     : (f2 + (size_t)(jbase - 2048) * 128);
  const int t = threadIdx.x;
  const int l = t & 63;
  const int wid = t >> 6;
  const int wy = wid >> 1, wx = wid & 1;
  const int rr = l & 15;
  const int q = l >> 4;
  const int sw = l & 7;

  f32x4 acc[4][4];
#pragma unroll
  for (int mi = 0; mi < 4; ++mi)
#pragma unroll
    for (int ni = 0; ni < 4; ++ni) acc[mi][ni] = (f32x4)0.0f;

  const int kq = t & 15;
  const int r0 = t >> 4;
  const int stc = ((kq >> 1) ^ (r0 & 7)) * 8 + (kq & 1) * 4;

  for (int kc = 0; kc < 2; ++kc) {
    __syncthreads();  // protects LDS vs prior readers (incl. prior tile)
#pragma unroll
    for (int p = 0; p < 8; ++p) {
      const int r = r0 + 16 * p;
      const float4 va = *(const float4*)(asrc + (size_t)r * 128 + kc * 64 + kq * 4);
      ushort4_t ha, la;
      HL s;
      s = split1(va.x); ha.x = s.h; la.x = s.l;
      s = split1(va.y); ha.y = s.h; la.y = s.l;
      s = split1(va.z); ha.z = s.h; la.z = s.l;
      s = split1(va.w); ha.w = s.h; la.w = s.l;
      *(ushort4_t*)&Ah[r][stc] = ha;
      *(ushort4_t*)&Al[r][stc] = la;
      if (!diag) {
        const float4 vb = *(const float4*)(bsrc + (size_t)r * 128 + kc * 64 + kq * 4);
        ushort4_t hb, lb;
        s = split1(vb.x); hb.x = s.h; lb.x = s.l;
        s = split1(vb.y); hb.y = s.h; lb.y = s.l;
        s = split1(vb.z); hb.z = s.h; lb.z = s.l;
        s = split1(vb.w); hb.w = s.h; lb.w = s.l;
        *(ushort4_t*)&Bh[r][stc] = hb;
        *(ushort4_t*)&Bl[r][stc] = lb;
      }
    }
    __syncthreads();

#pragma unroll
    for (int s = 0; s < 2; ++s) {
      const int pb = ((((s << 2) | q)) ^ sw) << 3;
      short8 afh[4], afl[4], bfh[4], bfl[4];
#pragma unroll
      for (int mi = 0; mi < 4; ++mi) {
        const int ar = wy * 64 + mi * 16 + rr;
        afh[mi] = *(const short8*)&Ah[ar][pb];
        afl[mi] = *(const short8*)&Al[ar][pb];
        const int br = wx * 64 + mi * 16 + rr;
        bfh[mi] = diag ? *(const short8*)&Ah[br][pb]
                       : *(const short8*)&Bh[br][pb];
        bfl[mi] = diag ? *(const short8*)&Al[br][pb]
                       : *(const short8*)&Bl[br][pb];
      }
#pragma unroll
      for (int mi = 0; mi < 4; ++mi)
#pragma unroll
        for (int ni = 0; ni < 4; ++ni) {
          acc[mi][ni] = __builtin_amdgcn_mfma_f32_16x16x32_bf16(
              afh[mi], bfh[ni], acc[mi][ni], 0, 0, 0);
          acc[mi][ni] = __builtin_amdgcn_mfma_f32_16x16x32_bf16(
              afh[mi], bfl[ni], acc[mi][ni], 0, 0, 0);
          acc[mi][ni] = __builtin_amdgcn_mfma_f32_16x16x32_bf16(
              afl[mi], bfh[ni], acc[mi][ni], 0, 0, 0);
        }
    }
  }

  // -------- epilogue: LDS-transpose reductions (no shuffles, no atomics) ---
  const bool off = !diag;
  const float cw = ((ibase < 2048) != (jbase < 2048)) ? 0.5f : 1.0f;

  float* RowPn = (float*)&Ah[0][0];   // overlays: tile LDS dead after MFMA
  float* RowPl = (float*)&Al[0][0];
  float* RowPm = (float*)&Bh[0][0];
  float* ColPn = (float*)&Bl[0][0];
  float* ColPl = ColPn + 1024;
  float* ColPm = ColPn + 2048;

  int gj[4], lj[4];
#pragma unroll
  for (int ni = 0; ni < 4; ++ni) {
    gj[ni] = jbase + wx * 64 + ni * 16 + rr;
    lj[ni] = labf(gj[ni], s_class2);
  }

  float cnsum[4], cnmax[4], clsum[4];
#pragma unroll
  for (int ni = 0; ni < 4; ++ni) {
    cnsum[ni] = 0.f; cnmax[ni] = 0.f; clsum[ni] = 0.f;
  }

  __syncthreads();  // all waves done reading tile LDS before overlay writes

#pragma unroll
  for (int mi = 0; mi < 4; ++mi) {
#pragma unroll
    for (int reg = 0; reg < 4; ++reg) {
      const int gi = ibase + wy * 64 + mi * 16 + q * 4 + reg;
      const int li = labf(gi, s_class2);
      float rn = 0.f, rl = 0.f, rm = 0.f;
#pragma unroll
      for (int ni = 0; ni < 4; ++ni) {
        const int gjj = gj[ni];
        if (gi == gjj) continue;
        const float logit = acc[mi][ni][reg] * TEMP;
        const float e = __expf(logit);
        if (li == lj[ni]) {
          rl += logit;
          posbuf[(size_t)gi * 128 + slotf(gjj, li, s_v2b)] = e;
          if (off) {
            clsum[ni] += logit;
            posbuf[(size_t)gjj * 128 + slotf(gi, li, s_v2b)] = e;
          }
        } else {
          rn += e;
          rm = fmaxf(rm, e);
          if (off) {
            cnsum[ni] += e;
            cnmax[ni] = fmaxf(cnmax[ni], e);
          }
        }
      }
      const int widx = ((mi * 4 + reg) * 4 + wid) * 64 + l;
      RowPn[widx] = rn;
      RowPl[widx] = rl;
      RowPm[widx] = rm;
    }
  }
  if (off) {
#pragma unroll
    for (int ni = 0; ni < 4; ++ni) {
      const int widx = (ni * 4 + wid) * 64 + l;
      ColPn[widx] = cnsum[ni];
      ColPl[widx] = clsum[ni];
      ColPm[widx] = cnmax[ni];
    }
  }
  __syncthreads();

  // phase 2a: row reduce — thread t owns (row r = t>>1, col-half h = t&1)
  {
    const int r = t >> 1, h = t & 1;
    const int g = (((r >> 4) & 3) * 4) + (r & 3);      // mi*4+reg
    const int w2 = (r >> 6) * 2 + h;                   // wy*2+wx
    const int base = (g * 4 + w2) * 64 + ((r >> 2) & 3) * 16;
    const float4* pn = (const float4*)&RowPn[base];
    const float4* pl = (const float4*)&RowPl[base];
    const float4* pm = (const float4*)&RowPm[base];
    float ns = 0.f, ls = 0.f, nm = 0.f;
#pragma unroll
    for (int i = 0; i < 4; ++i) {
      const float4 a = pn[i], b = pl[i], c = pm[i];
      ns += a.x + a.y + a.z + a.w;
      ls += b.x + b.y + b.z + b.w;
      nm = fmaxf(nm, fmaxf(fmaxf(c.x, c.y), fmaxf(c.z, c.w)));
    }
    float4 v; v.x = ns; v.y = 0.f; v.z = cw * ls; v.w = nm;
    P4[(size_t)(ibase + r) * 64 + (bj * 2 + h)] = v;
  }

  // phase 2b: col reduce (off-diag only)
  if (off) {
    const int c = t >> 1, hy = t & 1;
    const int w2 = hy * 2 + (c >> 6);
    const int base = (((c >> 4) & 3) * 4 + w2) * 64 + (c & 15);
    float ns = 0.f, ls = 0.f, nm = 0.f;
#pragma unroll
    for (int q4 = 0; q4 < 4; ++q4) {
      const int idx = base + q4 * 16;
      ns += ColPn[idx];
      ls += ColPl[idx];
      nm = fmaxf(nm, ColPm[idx]);
    }
    float4 v; v.x = ns; v.y = 0.f; v.z = cw * ls; v.w = nm;
    P4[(size_t)(jbase + c) * 64 + (bi * 2 + hy)] = v;
  }
}

// 512 blocks = 2/CU: 496 off-diagonal tiles + 16 blocks x 2 diagonal tiles.
__global__ __launch_bounds__(256, 2) void main_kernel(
    const float* __restrict__ f1, const float* __restrict__ f2,
    const int* __restrict__ ov_raw, float4* __restrict__ P4,
    float* __restrict__ posbuf) {
  __shared__ unsigned short Ah[128][64], Al[128][64];
  __shared__ unsigned short Bh[128][64], Bl[128][64];
  __shared__ int s_class2[32], s_v2b[64], s_ov[32];

  decode_ov(ov_raw, s_class2, s_v2b, s_ov);

  const int bid = blockIdx.x;
  if (bid < 496) {
    int idx = bid, bi = 0;
    while (idx >= 31 - bi) { idx -= 31 - bi; ++bi; }
    const int bj = bi + 1 + idx;
    compute_tile(bi, bj, false, f1, f2, Ah, Al, Bh, Bl, s_class2, s_v2b, P4,
                 posbuf);
  } else {
    const int d = (bid - 496) * 2;
    compute_tile(d, d, true, f1, f2, Ah, Al, Bh, Bl, s_class2, s_v2b, P4,
                 posbuf);
    compute_tile(d + 1, d + 1, true, f1, f2, Ah, Al, Bh, Bl, s_class2, s_v2b,
                 P4, posbuf);
  }
}

// 256 blocks x 256, one wave per 4 rows; last block writes the 2 outputs.
// pcw is analytic: 95 if the row's class spans both views, else 63.
__global__ __launch_bounds__(256) void finalize_kernel(
    const int* __restrict__ ov_raw, const float4* __restrict__ P4,
    const float* __restrict__ posbuf, float* __restrict__ accum,
    int* __restrict__ counter, float* __restrict__ out) {
  __shared__ int s_class2[32], s_v2b[64], s_ov[32];
  __shared__ float sc[4], sp[4], sl[4];
  decode_ov(ov_raw, s_class2, s_v2b, s_ov);
  __syncthreads();

  const int t = threadIdx.x;
  const int w = t >> 6, lane = t & 63;
  float cnt_acc = 0.f, pos_acc = 0.f, loss_acc = 0.f;
  const int rbase = blockIdx.x * 16 + w * 4;
  for (int i = 0; i < 4; ++i) {
    const int row = rbase + i;
    float4 p = P4[(size_t)row * 64 + lane];
#pragma unroll
    for (int m = 1; m < 64; m <<= 1) {
      p.x += __shfl_xor(p.x, m, 64);
      p.z += __shfl_xor(p.z, m, 64);
      p.w = fmaxf(p.w, __shfl_xor(p.w, m, 64));
    }
    const float nmax = p.w;
    const float2 pv = *(const float2*)&posbuf[(size_t)row * 128 + lane * 2];
    const int c = labf(row, s_class2);
    const bool both = (row < 2048) ? (s_ov[c] != 0) : (c < 32);
    const int size = both ? 128 : 64;
    int selfslot;
    if (row < 2048) selfslot = row - (c << 6);
    else selfslot = ((c < 32) ? 64 : 0) + (row - 2048 - (s_v2b[c] << 6));
    const int s0 = lane * 2;
    int h = 0;
    if (s0 < size && s0 != selfslot && pv.x > nmax) h++;
    if (s0 + 1 < size && s0 + 1 != selfslot && pv.y > nmax) h++;
    cnt_acc += (float)h;
    if (lane == 0) {
      const float pcw = both ? 95.f : 63.f;
      loss_acc += logf(p.x) * pcw - p.z;
      pos_acc += (float)(size - 1);
    }
  }
#pragma unroll
  for (int m = 1; m < 64; m <<= 1) {
    cnt_acc += __shfl_xor(cnt_acc, m, 64);
    pos_acc += __shfl_xor(pos_acc, m, 64);
    loss_acc += __shfl_xor(loss_acc, m, 64);
  }
  if (lane == 0) { sc[w] = cnt_acc; sp[w] = pos_acc; sl[w] = loss_acc; }
  __syncthreads();
  if (t == 0) {
    atomicAdd(&accum[0], sc[0] + sc[1] + sc[2] + sc[3]);
    atomicAdd(&accum[1], sp[0] + sp[1] + sp[2] + sp[3]);
    atomicAdd(&accum[2], sl[0] + sl[1] + sl[2] + sl[3]);
    __threadfence();
    const int prev = atomicAdd(counter, 1);
    if (prev == 255) {
      const float c = atomicAdd(&accum[0], 0.0f);
      const float tp = atomicAdd(&accum[1], 0.0f);
      const float lo = atomicAdd(&accum[2], 0.0f);
      out[0] = c / tp;
      out[1] = lo / tp;
    }
  }
}

extern "C" void kernel_launch(void* const* d_in, const int* in_sizes, int n_in,
                              void* d_out, int out_size, void* d_ws,
                              size_t ws_size, hipStream_t stream) {
  const float* f1 = (const float*)d_in[0];
  const float* f2 = (const float*)d_in[1];
  const int* ov = (const int*)d_in[2];
  float* out = (float*)d_out;

  float* wsf = (float*)d_ws;
  int* wsi = (int*)d_ws;
  float* accum  = wsf;                 // 3 floats
  int* counter  = wsi + 3;             // 1 int
  float* posbuf = wsf + 16;            // 4096*128 -> ends at float 524304
  float4* P4    = (float4*)(wsf + 524304);  // 4096*64 float4 = 4 MB

  (void)hipMemsetAsync(accum, 0, 32, stream);

  main_kernel<<<512, 256, 0, stream>>>(f1, f2, ov, P4, posbuf);
  finalize_kernel<<<256, 256, 0, stream>>>(ov, P4, posbuf, accum, counter,
                                           out);
}